// Round 1
// baseline (469.684 us; speedup 1.0000x reference)
//
#include <hip/hip_runtime.h>
#include <stdint.h>
#include <limits.h>

#define FEAT 64
#define QMINF (-128.0f)
#define QMAXF (127.0f)

// monotone float<->uint order mapping for atomic min/max on floats
__device__ __forceinline__ unsigned f2ord(float f) {
    unsigned u = __float_as_uint(f);
    return (u & 0x80000000u) ? ~u : (u | 0x80000000u);
}
__device__ __forceinline__ float ord2f(unsigned o) {
    unsigned u = (o & 0x80000000u) ? (o & 0x7FFFFFFFu) : ~o;
    return __uint_as_float(u);
}

__device__ __forceinline__ float clampf(float v, float lo, float hi) {
    return fminf(fmaxf(v, lo), hi);
}

// ws scalar layout (uint/int words):
// [0] gmin_ord (msg min, ordered uint)   [1] gmax_ord (msg max)
// [2] isum_min (int)                     [3] isum_max (int)
__global__ void k_init(unsigned* s) {
    if (threadIdx.x == 0) {
        s[0] = 0xFFFFFFFFu;
        s[1] = 0u;
        ((int*)s)[2] = INT_MAX;
        ((int*)s)[3] = INT_MIN;
    }
}

// one wave per node row: min/max of 64 feats
__global__ void k_rowminmax(const float* __restrict__ x,
                            float* __restrict__ rowmin, float* __restrict__ rowmax,
                            int nrows) {
    int gid = blockIdx.x * blockDim.x + threadIdx.x;
    int row = gid >> 6;
    int lane = threadIdx.x & 63;
    if (row >= nrows) return;
    float v = x[row * FEAT + lane];
    float mn = v, mx = v;
#pragma unroll
    for (int o = 32; o >= 1; o >>= 1) {
        mn = fminf(mn, __shfl_xor(mn, o));
        mx = fmaxf(mx, __shfl_xor(mx, o));
    }
    if (lane == 0) { rowmin[row] = mn; rowmax[row] = mx; }
}

// min/max over x[src] via per-node row min/max
__global__ void k_edgeminmax(const int* __restrict__ src, int E, int N,
                             const float* __restrict__ rowmin,
                             const float* __restrict__ rowmax,
                             unsigned* gord) {
    float mn = INFINITY, mx = -INFINITY;
    int stride = gridDim.x * blockDim.x;
    for (int i = blockIdx.x * blockDim.x + threadIdx.x; i < E; i += stride) {
        unsigned s = (unsigned)src[i];
        if (s < (unsigned)N) {
            mn = fminf(mn, rowmin[s]);
            mx = fmaxf(mx, rowmax[s]);
        }
    }
#pragma unroll
    for (int o = 32; o >= 1; o >>= 1) {
        mn = fminf(mn, __shfl_xor(mn, o));
        mx = fmaxf(mx, __shfl_xor(mx, o));
    }
    if ((threadIdx.x & 63) == 0) {
        atomicMin(&gord[0], f2ord(mn));
        atomicMax(&gord[1], f2ord(mx));
    }
}

// one wave per edge: quantize message row to integer levels, scatter-add int32
__global__ void k_scatter(const float* __restrict__ x,
                          const int* __restrict__ src, const int* __restrict__ dst,
                          int E, int N,
                          const unsigned* __restrict__ gord,
                          int* __restrict__ isum) {
    int wid = (blockIdx.x * blockDim.x + threadIdx.x) >> 6;
    int lane = threadIdx.x & 63;
    if (wid >= E) return;
    float mnv = ord2f(gord[0]);
    float mxv = ord2f(gord[1]);
    float scale = fmaxf((mxv - mnv) / 255.0f, 1e-8f);
    float zp = clampf(rintf(QMINF - mnv / scale), QMINF, QMAXF);
    unsigned s = (unsigned)src[wid];
    unsigned d = (unsigned)dst[wid];
    if (s >= (unsigned)N || d >= (unsigned)N) return;
    float v = x[s * FEAT + lane];
    float q = clampf(rintf(v / scale) + zp, QMINF, QMAXF);
    int k = (int)(q - zp);  // exact integral float -> int, |k| <= 255
    atomicAdd(&isum[d * FEAT + lane], k);
}

// int min/max over isum (int4-vectorized)
__global__ void k_aggminmax(const int4* __restrict__ isum, int n4, unsigned* gord) {
    int* smm = (int*)gord;
    int mn = INT_MAX, mx = INT_MIN;
    int stride = gridDim.x * blockDim.x;
    for (int i = blockIdx.x * blockDim.x + threadIdx.x; i < n4; i += stride) {
        int4 v = isum[i];
        mn = min(mn, min(min(v.x, v.y), min(v.z, v.w)));
        mx = max(mx, max(max(v.x, v.y), max(v.z, v.w)));
    }
#pragma unroll
    for (int o = 32; o >= 1; o >>= 1) {
        mn = min(mn, __shfl_xor(mn, o));
        mx = max(mx, __shfl_xor(mx, o));
    }
    if ((threadIdx.x & 63) == 0) {
        atomicMin(&smm[2], mn);
        atomicMax(&smm[3], mx);
    }
}

__device__ __forceinline__ float dq_apply(float v, float scale, float zp) {
    float q = clampf(rintf(v / scale) + zp, QMINF, QMAXF);
    return (q - zp) * scale;
}

// out = fq3(fq2(isum * scale1)); reads int4 and writes float4 in place (d_out)
__global__ void k_final(const int4* __restrict__ isum, float4* __restrict__ out,
                        int n4, const unsigned* __restrict__ gord) {
    const int* smm = (const int*)gord;
    float mnv = ord2f(gord[0]);
    float mxv = ord2f(gord[1]);
    float scale1 = fmaxf((mxv - mnv) / 255.0f, 1e-8f);

    float mn2 = (float)smm[2] * scale1;
    float mx2 = (float)smm[3] * scale1;
    float scale2 = fmaxf((mx2 - mn2) / 255.0f, 1e-8f);
    float zp2 = clampf(rintf(QMINF - mn2 / scale2), QMINF, QMAXF);

    // quant-3 params: dq2 is monotone, so min/max(dq2(agg)) = dq2(min/max(agg))
    float mn3 = dq_apply(mn2, scale2, zp2);
    float mx3 = dq_apply(mx2, scale2, zp2);
    float scale3 = fmaxf((mx3 - mn3) / 255.0f, 1e-8f);
    float zp3 = clampf(rintf(QMINF - mn3 / scale3), QMINF, QMAXF);

    int stride = gridDim.x * blockDim.x;
    for (int i = blockIdx.x * blockDim.x + threadIdx.x; i < n4; i += stride) {
        int4 v = isum[i];
        float4 o;
        float a;
        a = dq_apply((float)v.x * scale1, scale2, zp2); o.x = dq_apply(a, scale3, zp3);
        a = dq_apply((float)v.y * scale1, scale2, zp2); o.y = dq_apply(a, scale3, zp3);
        a = dq_apply((float)v.z * scale1, scale2, zp2); o.z = dq_apply(a, scale3, zp3);
        a = dq_apply((float)v.w * scale1, scale2, zp2); o.w = dq_apply(a, scale3, zp3);
        out[i] = o;
    }
}

extern "C" void kernel_launch(void* const* d_in, const int* in_sizes, int n_in,
                              void* d_out, int out_size, void* d_ws, size_t ws_size,
                              hipStream_t stream) {
    const float* x = (const float*)d_in[0];
    const int* ei = (const int*)d_in[1];

    int NF = in_sizes[0];        // N * 64
    int N = NF / FEAT;
    int E = in_sizes[1] / 2;     // edge_index is [2, E] row-major
    const int* src = ei;
    const int* dst = ei + E;

    unsigned* scal = (unsigned*)d_ws;
    float* rowmin = (float*)((char*)d_ws + 64);
    float* rowmax = rowmin + N;
    int* isum = (int*)d_out;     // reuse output buffer as int32 accumulator

    // zero the accumulator every call (harness does not re-poison between replays)
    hipMemsetAsync(d_out, 0, (size_t)NF * sizeof(int), stream);
    k_init<<<1, 64, 0, stream>>>(scal);

    // per-node row min/max: one wave per row
    k_rowminmax<<<(N * 64 + 255) / 256, 256, 0, stream>>>(x, rowmin, rowmax, N);

    // msg (gathered) global min/max over edges
    k_edgeminmax<<<1024, 256, 0, stream>>>(src, E, N, rowmin, rowmax, scal);

    // quantize messages to integer levels and scatter-add (int atomics, deterministic)
    k_scatter<<<(E + 3) / 4, 256, 0, stream>>>(x, src, dst, E, N, scal, isum);

    // agg min/max (integer domain)
    k_aggminmax<<<2048, 256, 0, stream>>>((const int4*)isum, NF / 4, scal);

    // dequant chain + final output (in place over d_out)
    k_final<<<2048, 256, 0, stream>>>((const int4*)isum, (float4*)d_out, NF / 4, scal);
}

// Round 2
// 194.130 us; speedup vs baseline: 2.4194x; 2.4194x over previous
//
#include <hip/hip_runtime.h>
#include <stdint.h>
#include <limits.h>

#define FEAT 64
#define QMINF (-128.0f)
#define QMAXF (127.0f)
#define RBLOCKS 256   // partial-reduction blocks == threads in params kernels

__device__ __forceinline__ float clampf(float v, float lo, float hi) {
    return fminf(fmaxf(v, lo), hi);
}

__device__ __forceinline__ float dq_apply(float v, float scale, float zp) {
    float q = clampf(rintf(v / scale) + zp, QMINF, QMAXF);
    return (q - zp) * scale;
}

// ---- block-level min/max reductions (no global atomics) ----
__device__ __forceinline__ void block_minmax_f(float& mn, float& mx) {
#pragma unroll
    for (int o = 32; o >= 1; o >>= 1) {
        mn = fminf(mn, __shfl_xor(mn, o));
        mx = fmaxf(mx, __shfl_xor(mx, o));
    }
    __shared__ float smn[4], smx[4];
    int wave = threadIdx.x >> 6;
    if ((threadIdx.x & 63) == 0) { smn[wave] = mn; smx[wave] = mx; }
    __syncthreads();
    if (threadIdx.x == 0) {
        int nw = (blockDim.x + 63) >> 6;
        for (int w = 1; w < nw; ++w) {
            mn = fminf(mn, smn[w]);
            mx = fmaxf(mx, smx[w]);
        }
    }
}

__device__ __forceinline__ void block_minmax_i(int& mn, int& mx) {
#pragma unroll
    for (int o = 32; o >= 1; o >>= 1) {
        mn = min(mn, __shfl_xor(mn, o));
        mx = max(mx, __shfl_xor(mx, o));
    }
    __shared__ int smn[4], smx[4];
    int wave = threadIdx.x >> 6;
    if ((threadIdx.x & 63) == 0) { smn[wave] = mn; smx[wave] = mx; }
    __syncthreads();
    if (threadIdx.x == 0) {
        int nw = (blockDim.x + 63) >> 6;
        for (int w = 1; w < nw; ++w) {
            mn = min(mn, smn[w]);
            mx = max(mx, smx[w]);
        }
    }
}

// one wave per node row: min/max of 64 feats
__global__ void k_rowminmax(const float* __restrict__ x,
                            float* __restrict__ rowmin, float* __restrict__ rowmax,
                            int nrows) {
    int gid = blockIdx.x * blockDim.x + threadIdx.x;
    int row = gid >> 6;
    int lane = threadIdx.x & 63;
    if (row >= nrows) return;
    float v = x[row * FEAT + lane];
    float mn = v, mx = v;
#pragma unroll
    for (int o = 32; o >= 1; o >>= 1) {
        mn = fminf(mn, __shfl_xor(mn, o));
        mx = fmaxf(mx, __shfl_xor(mx, o));
    }
    if (lane == 0) { rowmin[row] = mn; rowmax[row] = mx; }
}

// min/max over x[src] via per-node row min/max -> per-block partials (no atomics)
__global__ void k_edgeminmax(const int* __restrict__ src, int E, int N,
                             const float* __restrict__ rowmin,
                             const float* __restrict__ rowmax,
                             float* __restrict__ pmin, float* __restrict__ pmax) {
    float mn = INFINITY, mx = -INFINITY;
    int stride = gridDim.x * blockDim.x;
    for (int i = blockIdx.x * blockDim.x + threadIdx.x; i < E; i += stride) {
        unsigned s = (unsigned)src[i];
        if (s < (unsigned)N) {
            mn = fminf(mn, rowmin[s]);
            mx = fmaxf(mx, rowmax[s]);
        }
    }
    block_minmax_f(mn, mx);
    if (threadIdx.x == 0) { pmin[blockIdx.x] = mn; pmax[blockIdx.x] = mx; }
}

// single block: reduce partials, compute scale1/zp1
__global__ void k_params1(const float* __restrict__ pmin, const float* __restrict__ pmax,
                          float* __restrict__ par) {
    float mn = pmin[threadIdx.x];
    float mx = pmax[threadIdx.x];
    block_minmax_f(mn, mx);
    if (threadIdx.x == 0) {
        float scale = fmaxf((mx - mn) / 255.0f, 1e-8f);
        float zp = clampf(rintf(QMINF - mn / scale), QMINF, QMAXF);
        par[0] = scale;
        par[1] = zp;
    }
}

// one wave per edge: quantize message row to integer levels, scatter-add int32
__global__ void k_scatter(const float* __restrict__ x,
                          const int* __restrict__ src, const int* __restrict__ dst,
                          int E, int N,
                          const float* __restrict__ par,
                          int* __restrict__ isum) {
    int wid = (blockIdx.x * blockDim.x + threadIdx.x) >> 6;
    int lane = threadIdx.x & 63;
    if (wid >= E) return;
    float scale = par[0];
    float zp = par[1];
    unsigned s = (unsigned)src[wid];
    unsigned d = (unsigned)dst[wid];
    if (s >= (unsigned)N || d >= (unsigned)N) return;
    float v = x[s * FEAT + lane];
    float q = clampf(rintf(v / scale) + zp, QMINF, QMAXF);
    int k = (int)(q - zp);  // exact integral float -> int, |k| <= 255
    atomicAdd(&isum[d * FEAT + lane], k);
}

// int min/max over isum (int4-vectorized) -> per-block partials
__global__ void k_aggminmax(const int4* __restrict__ isum, int n4,
                            int* __restrict__ ipmin, int* __restrict__ ipmax) {
    int mn = INT_MAX, mx = INT_MIN;
    int stride = gridDim.x * blockDim.x;
    for (int i = blockIdx.x * blockDim.x + threadIdx.x; i < n4; i += stride) {
        int4 v = isum[i];
        mn = min(mn, min(min(v.x, v.y), min(v.z, v.w)));
        mx = max(mx, max(max(v.x, v.y), max(v.z, v.w)));
    }
    block_minmax_i(mn, mx);
    if (threadIdx.x == 0) { ipmin[blockIdx.x] = mn; ipmax[blockIdx.x] = mx; }
}

// single block: reduce int partials, derive scale2/zp2/scale3/zp3
__global__ void k_params2(const int* __restrict__ ipmin, const int* __restrict__ ipmax,
                          float* __restrict__ par) {
    int mn = ipmin[threadIdx.x];
    int mx = ipmax[threadIdx.x];
    block_minmax_i(mn, mx);
    if (threadIdx.x == 0) {
        float scale1 = par[0];
        float mn2 = (float)mn * scale1;
        float mx2 = (float)mx * scale1;
        float scale2 = fmaxf((mx2 - mn2) / 255.0f, 1e-8f);
        float zp2 = clampf(rintf(QMINF - mn2 / scale2), QMINF, QMAXF);
        // dq2 is monotone -> quant-3 range from the two scalars
        float mn3 = dq_apply(mn2, scale2, zp2);
        float mx3 = dq_apply(mx2, scale2, zp2);
        float scale3 = fmaxf((mx3 - mn3) / 255.0f, 1e-8f);
        float zp3 = clampf(rintf(QMINF - mn3 / scale3), QMINF, QMAXF);
        par[2] = scale2;
        par[3] = zp2;
        par[4] = scale3;
        par[5] = zp3;
    }
}

// out = fq3(fq2(isum * scale1)); reads int4 and writes float4 in place (d_out)
__global__ void k_final(const int4* __restrict__ isum, float4* __restrict__ out,
                        int n4, const float* __restrict__ par) {
    float scale1 = par[0];
    float scale2 = par[2], zp2 = par[3];
    float scale3 = par[4], zp3 = par[5];

    int stride = gridDim.x * blockDim.x;
    for (int i = blockIdx.x * blockDim.x + threadIdx.x; i < n4; i += stride) {
        int4 v = isum[i];
        float4 o;
        float a;
        a = dq_apply((float)v.x * scale1, scale2, zp2); o.x = dq_apply(a, scale3, zp3);
        a = dq_apply((float)v.y * scale1, scale2, zp2); o.y = dq_apply(a, scale3, zp3);
        a = dq_apply((float)v.z * scale1, scale2, zp2); o.z = dq_apply(a, scale3, zp3);
        a = dq_apply((float)v.w * scale1, scale2, zp2); o.w = dq_apply(a, scale3, zp3);
        out[i] = o;
    }
}

extern "C" void kernel_launch(void* const* d_in, const int* in_sizes, int n_in,
                              void* d_out, int out_size, void* d_ws, size_t ws_size,
                              hipStream_t stream) {
    const float* x = (const float*)d_in[0];
    const int* ei = (const int*)d_in[1];

    int NF = in_sizes[0];        // N * 64
    int N = NF / FEAT;
    int E = in_sizes[1] / 2;     // edge_index is [2, E] row-major
    const int* src = ei;
    const int* dst = ei + E;

    // ws layout
    float* par    = (float*)d_ws;            // 16 floats: scale1,zp1,scale2,zp2,scale3,zp3
    float* rowmin = par + 16;                // N
    float* rowmax = rowmin + N;              // N
    float* pmin   = rowmax + N;              // RBLOCKS
    float* pmax   = pmin + RBLOCKS;          // RBLOCKS
    int*   ipmin  = (int*)(pmax + RBLOCKS);  // RBLOCKS
    int*   ipmax  = ipmin + RBLOCKS;         // RBLOCKS

    int* isum = (int*)d_out;     // reuse output buffer as int32 accumulator

    // zero the accumulator every call (harness does not re-poison between replays)
    hipMemsetAsync(d_out, 0, (size_t)NF * sizeof(int), stream);

    // per-node row min/max: one wave per row
    k_rowminmax<<<(N * 64 + 255) / 256, 256, 0, stream>>>(x, rowmin, rowmax, N);

    // msg (gathered) global min/max over edges -> partials -> params1
    k_edgeminmax<<<RBLOCKS, 256, 0, stream>>>(src, E, N, rowmin, rowmax, pmin, pmax);
    k_params1<<<1, RBLOCKS, 0, stream>>>(pmin, pmax, par);

    // quantize messages to integer levels and scatter-add (int atomics, deterministic)
    k_scatter<<<(E + 3) / 4, 256, 0, stream>>>(x, src, dst, E, N, par, isum);

    // agg min/max (integer domain) -> partials -> params2
    k_aggminmax<<<RBLOCKS, 256, 0, stream>>>((const int4*)isum, NF / 4, ipmin, ipmax);
    k_params2<<<1, RBLOCKS, 0, stream>>>(ipmin, ipmax, par);

    // dequant chain + final output (in place over d_out)
    k_final<<<1024, 256, 0, stream>>>((const int4*)isum, (float4*)d_out, NF / 4, par);
}

// Round 3
// 159.821 us; speedup vs baseline: 2.9388x; 1.2147x over previous
//
#include <hip/hip_runtime.h>
#include <stdint.h>
#include <limits.h>

#define FEAT 64
#define QMINF (-128.0f)
#define QMAXF (127.0f)
#define RBLOCKS 256   // partial-reduction blocks == threads in params kernels

__device__ __forceinline__ float clampf(float v, float lo, float hi) {
    return fminf(fmaxf(v, lo), hi);
}

__device__ __forceinline__ float dq_apply(float v, float scale, float zp) {
    float q = clampf(rintf(v / scale) + zp, QMINF, QMAXF);
    return (q - zp) * scale;
}

// ---- block-level min/max reductions (no global atomics) ----
__device__ __forceinline__ void block_minmax_f(float& mn, float& mx) {
#pragma unroll
    for (int o = 32; o >= 1; o >>= 1) {
        mn = fminf(mn, __shfl_xor(mn, o));
        mx = fmaxf(mx, __shfl_xor(mx, o));
    }
    __shared__ float smn[4], smx[4];
    int wave = threadIdx.x >> 6;
    if ((threadIdx.x & 63) == 0) { smn[wave] = mn; smx[wave] = mx; }
    __syncthreads();
    if (threadIdx.x == 0) {
        int nw = (blockDim.x + 63) >> 6;
        for (int w = 1; w < nw; ++w) {
            mn = fminf(mn, smn[w]);
            mx = fmaxf(mx, smx[w]);
        }
    }
}

__device__ __forceinline__ void block_minmax_i(int& mn, int& mx) {
#pragma unroll
    for (int o = 32; o >= 1; o >>= 1) {
        mn = min(mn, __shfl_xor(mn, o));
        mx = max(mx, __shfl_xor(mx, o));
    }
    __shared__ int smn[4], smx[4];
    int wave = threadIdx.x >> 6;
    if ((threadIdx.x & 63) == 0) { smn[wave] = mn; smx[wave] = mx; }
    __syncthreads();
    if (threadIdx.x == 0) {
        int nw = (blockDim.x + 63) >> 6;
        for (int w = 1; w < nw; ++w) {
            mn = min(mn, smn[w]);
            mx = max(mx, smx[w]);
        }
    }
}

// one wave per node row: min/max of 64 feats
__global__ void k_rowminmax(const float* __restrict__ x,
                            float* __restrict__ rowmin, float* __restrict__ rowmax,
                            int nrows) {
    int gid = blockIdx.x * blockDim.x + threadIdx.x;
    int row = gid >> 6;
    int lane = threadIdx.x & 63;
    if (row >= nrows) return;
    float v = x[row * FEAT + lane];
    float mn = v, mx = v;
#pragma unroll
    for (int o = 32; o >= 1; o >>= 1) {
        mn = fminf(mn, __shfl_xor(mn, o));
        mx = fmaxf(mx, __shfl_xor(mx, o));
    }
    if (lane == 0) { rowmin[row] = mn; rowmax[row] = mx; }
}

// fused: min/max over x[src] (via row min/max) + degree histogram over dst
__global__ void k_edgeminmax_hist(const int* __restrict__ src, const int* __restrict__ dst,
                                  int E, int N,
                                  const float* __restrict__ rowmin,
                                  const float* __restrict__ rowmax,
                                  float* __restrict__ pmin, float* __restrict__ pmax,
                                  int* __restrict__ deg) {
    float mn = INFINITY, mx = -INFINITY;
    int stride = gridDim.x * blockDim.x;
    for (int i = blockIdx.x * blockDim.x + threadIdx.x; i < E; i += stride) {
        unsigned s = (unsigned)src[i];
        unsigned d = (unsigned)dst[i];
        if (s < (unsigned)N) {
            mn = fminf(mn, rowmin[s]);
            mx = fmaxf(mx, rowmax[s]);
        }
        if (d < (unsigned)N) atomicAdd(&deg[d], 1);
    }
    block_minmax_f(mn, mx);
    if (threadIdx.x == 0) { pmin[blockIdx.x] = mn; pmax[blockIdx.x] = mx; }
}

// single block: reduce partials, compute scale1/zp1
__global__ void k_params1(const float* __restrict__ pmin, const float* __restrict__ pmax,
                          float* __restrict__ par) {
    float mn = pmin[threadIdx.x];
    float mx = pmax[threadIdx.x];
    block_minmax_f(mn, mx);
    if (threadIdx.x == 0) {
        float scale = fmaxf((mx - mn) / 255.0f, 1e-8f);
        float zp = clampf(rintf(QMINF - mn / scale), QMINF, QMAXF);
        par[0] = scale;
        par[1] = zp;
    }
}

// ---- exclusive scan of deg (N elems) -> off, 3-phase ----
__global__ void k_scan1(const int* __restrict__ deg, int* __restrict__ off,
                        int* __restrict__ bsum, int N) {
    __shared__ int tmp[1024];
    int gid = blockIdx.x * 1024 + threadIdx.x;
    int v = (gid < N) ? deg[gid] : 0;
    tmp[threadIdx.x] = v;
    __syncthreads();
#pragma unroll
    for (int o = 1; o < 1024; o <<= 1) {
        int t = (threadIdx.x >= o) ? tmp[threadIdx.x - o] : 0;
        __syncthreads();
        tmp[threadIdx.x] += t;
        __syncthreads();
    }
    if (gid < N) off[gid] = tmp[threadIdx.x] - v;  // exclusive
    if (threadIdx.x == 1023) bsum[blockIdx.x] = tmp[1023];
}

// single wave: exclusive scan of block sums (nb <= 64)
__global__ void k_scan2(int* __restrict__ bsum, int nb) {
    int lane = threadIdx.x & 63;
    int v = (lane < nb) ? bsum[lane] : 0;
    int s = v;
#pragma unroll
    for (int o = 1; o < 64; o <<= 1) {
        int t = __shfl_up(s, o);
        if (lane >= o) s += t;
    }
    if (lane < nb) bsum[lane] = s - v;  // exclusive
}

__global__ void k_scan3(int* __restrict__ off, const int* __restrict__ bsum, int N) {
    int gid = blockIdx.x * 1024 + threadIdx.x;
    if (gid < N) off[gid] += bsum[blockIdx.x];
}

// counting-sort bucket phase: sorted_src grouped by dst
__global__ void k_bucket(const int* __restrict__ src, const int* __restrict__ dst,
                         int E, int N,
                         const int* __restrict__ off, int* __restrict__ cnt,
                         int* __restrict__ ssrc) {
    int i = blockIdx.x * blockDim.x + threadIdx.x;
    if (i >= E) return;
    unsigned d = (unsigned)dst[i];
    unsigned s = (unsigned)src[i];
    if (d >= (unsigned)N || s >= (unsigned)N) return;
    int pos = off[d] + atomicAdd(&cnt[d], 1);
    ssrc[pos] = (int)s;
}

// one wave per destination node: gather+quantize+accumulate in register, one write
__global__ void k_gather_agg(const float* __restrict__ x,
                             const int* __restrict__ off, const int* __restrict__ deg,
                             const int* __restrict__ ssrc,
                             const float* __restrict__ par,
                             int* __restrict__ isum, int N) {
    int wid = (blockIdx.x * blockDim.x + threadIdx.x) >> 6;
    int lane = threadIdx.x & 63;
    if (wid >= N) return;
    float scale = par[0];
    float zp = par[1];
    int o0 = off[wid];
    int d = deg[wid];
    int acc = 0;
    int j = 0;
    for (; j + 2 <= d; j += 2) {
        int s0 = ssrc[o0 + j];
        int s1 = ssrc[o0 + j + 1];
        float v0 = x[(size_t)s0 * FEAT + lane];
        float v1 = x[(size_t)s1 * FEAT + lane];
        float q0 = clampf(rintf(v0 / scale) + zp, QMINF, QMAXF);
        float q1 = clampf(rintf(v1 / scale) + zp, QMINF, QMAXF);
        acc += (int)(q0 - zp) + (int)(q1 - zp);
    }
    if (j < d) {
        int s0 = ssrc[o0 + j];
        float v0 = x[(size_t)s0 * FEAT + lane];
        float q0 = clampf(rintf(v0 / scale) + zp, QMINF, QMAXF);
        acc += (int)(q0 - zp);
    }
    isum[(size_t)wid * FEAT + lane] = acc;
}

// int min/max over isum (int4-vectorized) -> per-block partials
__global__ void k_aggminmax(const int4* __restrict__ isum, int n4,
                            int* __restrict__ ipmin, int* __restrict__ ipmax) {
    int mn = INT_MAX, mx = INT_MIN;
    int stride = gridDim.x * blockDim.x;
    for (int i = blockIdx.x * blockDim.x + threadIdx.x; i < n4; i += stride) {
        int4 v = isum[i];
        mn = min(mn, min(min(v.x, v.y), min(v.z, v.w)));
        mx = max(mx, max(max(v.x, v.y), max(v.z, v.w)));
    }
    block_minmax_i(mn, mx);
    if (threadIdx.x == 0) { ipmin[blockIdx.x] = mn; ipmax[blockIdx.x] = mx; }
}

// single block: reduce int partials, derive scale2/zp2/scale3/zp3
__global__ void k_params2(const int* __restrict__ ipmin, const int* __restrict__ ipmax,
                          float* __restrict__ par) {
    int mn = ipmin[threadIdx.x];
    int mx = ipmax[threadIdx.x];
    block_minmax_i(mn, mx);
    if (threadIdx.x == 0) {
        float scale1 = par[0];
        float mn2 = (float)mn * scale1;
        float mx2 = (float)mx * scale1;
        float scale2 = fmaxf((mx2 - mn2) / 255.0f, 1e-8f);
        float zp2 = clampf(rintf(QMINF - mn2 / scale2), QMINF, QMAXF);
        // dq2 is monotone -> quant-3 range from the two scalars
        float mn3 = dq_apply(mn2, scale2, zp2);
        float mx3 = dq_apply(mx2, scale2, zp2);
        float scale3 = fmaxf((mx3 - mn3) / 255.0f, 1e-8f);
        float zp3 = clampf(rintf(QMINF - mn3 / scale3), QMINF, QMAXF);
        par[2] = scale2;
        par[3] = zp2;
        par[4] = scale3;
        par[5] = zp3;
    }
}

// out = fq3(fq2(isum * scale1)); reads int4 and writes float4 in place (d_out)
__global__ void k_final(const int4* __restrict__ isum, float4* __restrict__ out,
                        int n4, const float* __restrict__ par) {
    float scale1 = par[0];
    float scale2 = par[2], zp2 = par[3];
    float scale3 = par[4], zp3 = par[5];

    int stride = gridDim.x * blockDim.x;
    for (int i = blockIdx.x * blockDim.x + threadIdx.x; i < n4; i += stride) {
        int4 v = isum[i];
        float4 o;
        float a;
        a = dq_apply((float)v.x * scale1, scale2, zp2); o.x = dq_apply(a, scale3, zp3);
        a = dq_apply((float)v.y * scale1, scale2, zp2); o.y = dq_apply(a, scale3, zp3);
        a = dq_apply((float)v.z * scale1, scale2, zp2); o.z = dq_apply(a, scale3, zp3);
        a = dq_apply((float)v.w * scale1, scale2, zp2); o.w = dq_apply(a, scale3, zp3);
        out[i] = o;
    }
}

extern "C" void kernel_launch(void* const* d_in, const int* in_sizes, int n_in,
                              void* d_out, int out_size, void* d_ws, size_t ws_size,
                              hipStream_t stream) {
    const float* x = (const float*)d_in[0];
    const int* ei = (const int*)d_in[1];

    int NF = in_sizes[0];        // N * 64
    int N = NF / FEAT;
    int E = in_sizes[1] / 2;     // edge_index is [2, E] row-major
    const int* src = ei;
    const int* dst = ei + E;

    // ws layout (all 4-byte typed, ~4.3 MB total)
    float* par    = (float*)d_ws;            // 16 floats
    float* rowmin = par + 16;                // N
    float* rowmax = rowmin + N;              // N
    float* pmin   = rowmax + N;              // RBLOCKS
    float* pmax   = pmin + RBLOCKS;          // RBLOCKS
    int*   ipmin  = (int*)(pmax + RBLOCKS);  // RBLOCKS
    int*   ipmax  = ipmin + RBLOCKS;         // RBLOCKS
    int*   deg    = ipmax + RBLOCKS;         // N   (zeroed, contiguous with cnt)
    int*   cnt    = deg + N;                 // N   (zeroed)
    int*   off    = cnt + N;                 // N
    int*   bsum   = off + N;                 // 64
    int*   ssrc   = bsum + 64;               // E

    int* isum = (int*)d_out;     // reuse output buffer as int32 accumulator

    int NB = (N + 1023) / 1024;  // scan blocks (<= 64)

    // zero deg+cnt in one shot (contiguous)
    hipMemsetAsync(deg, 0, (size_t)2 * N * sizeof(int), stream);

    // per-node row min/max: one wave per row
    k_rowminmax<<<(N * 64 + 255) / 256, 256, 0, stream>>>(x, rowmin, rowmax, N);

    // msg (gathered) min/max partials + dst degree histogram in one edge pass
    k_edgeminmax_hist<<<RBLOCKS, 256, 0, stream>>>(src, dst, E, N, rowmin, rowmax,
                                                   pmin, pmax, deg);
    k_params1<<<1, RBLOCKS, 0, stream>>>(pmin, pmax, par);

    // exclusive scan deg -> off
    k_scan1<<<NB, 1024, 0, stream>>>(deg, off, bsum, N);
    k_scan2<<<1, 64, 0, stream>>>(bsum, NB);
    k_scan3<<<NB, 1024, 0, stream>>>(off, bsum, N);

    // counting-sort edges by destination
    k_bucket<<<(E + 255) / 256, 256, 0, stream>>>(src, dst, E, N, off, cnt, ssrc);

    // gather + quantize + register-accumulate, one write per node row
    k_gather_agg<<<(N * 64 + 255) / 256, 256, 0, stream>>>(x, off, deg, ssrc, par, isum, N);

    // agg min/max (integer domain) -> partials -> params2
    k_aggminmax<<<RBLOCKS, 256, 0, stream>>>((const int4*)isum, NF / 4, ipmin, ipmax);
    k_params2<<<1, RBLOCKS, 0, stream>>>(ipmin, ipmax, par);

    // dequant chain + final output (in place over d_out)
    k_final<<<1024, 256, 0, stream>>>((const int4*)isum, (float4*)d_out, NF / 4, par);
}